// Round 8
// baseline (1645.500 us; speedup 1.0000x reference)
//
#include <hip/hip_runtime.h>
#include <hip/hip_bf16.h>
#include <math.h>

// Problem dims
#define B_ 8
#define L_ 4096
#define F_ 512
#define H_ 512
#define P_ 256
#define DEPTH_ 6
#define M_ (B_*L_)      // 32768 rows
#define EPS_ 1e-5f

// scan chunking
#define NCH 128
#define CLEN 32         // NCH*CLEN == L_

typedef unsigned short u16;
typedef short short8 __attribute__((ext_vector_type(8)));
typedef float floatx4 __attribute__((ext_vector_type(4)));

typedef const __attribute__((address_space(1))) unsigned short* gas_p;
typedef __attribute__((address_space(3))) unsigned short* las_p;

// ---------- bf16 helpers (bit-level, header-proof) ----------
__device__ __forceinline__ u16 f2bf(float x) {
    union { float f; unsigned int u; } v; v.f = x;
    unsigned int u = v.u;
    unsigned int lsb = (u >> 16) & 1u;
    u += 0x7fffu + lsb;           // round-to-nearest-even
    return (u16)(u >> 16);
}
__device__ __forceinline__ float bf2f(u16 s) {
    union { unsigned int u; float f; } v; v.u = ((unsigned int)s) << 16;
    return v.f;
}
// fast gelu (tanh form, HW exp2/rcp)
__device__ __forceinline__ float gelu_f(float x) {
    float inner = x * (1.0f + 0.044715f * x * x);
    float e = __builtin_amdgcn_exp2f(2.3022083f * inner);
    float r = __builtin_amdgcn_rcpf(1.0f + e);
    return x - x * r;
}
// fast tanh
__device__ __forceinline__ float tanh_f(float y) {
    float e = __builtin_amdgcn_exp2f(2.88539008f * y);
    float r = __builtin_amdgcn_rcpf(1.0f + e);
    return 1.0f - 2.0f * r;
}

// fragment-major packed offset for weight Bt[n][k] (K = reduction dim):
// block (n16 = n/16, ks = k/32) -> 512 contiguous u16; inside:
// kseg=(k>>3)&3, row=n&15, j=k&7 -> kseg*128 + row*8 + j
__device__ __forceinline__ long dst_off(int n, int k, int K) {
    return ((long)((n >> 4) * (K >> 5) + (k >> 5))) * 512
         + ((k >> 3) & 3) * 128 + (n & 15) * 8 + (k & 7);
}

// ---------- GEMM: C[M,N] = A[M,K] @ Bt_packed, bf16 in, fp32 acc, bf16 out ----------
#define BM 128
#define BN 128
#define TPAD 136   // epilogue transpose row stride (u16): 272 B, 16B-aligned

enum { EPI_STORE = 0, EPI_BIAS = 1, EPI_BIAS_GELU = 2, EPI_DU_GELU_RES = 3, EPI_BIAS_RES = 4 };

// Grid: 1D, XCD-swizzled: id = 8*NT*g + 8*n + x, m-tile = 8g+x -> all N-tiles
// of an M-tile share id%8 (same XCD) -> A fetched into one L2 only.
// K-loop: BK=32, double-buffered LDS (2x16KB), prefetch next tile BEFORE
// computing current, ONE barrier per iter -> drain waits (latency - compute)
// instead of full load latency.
template<int EPI>
__global__ __launch_bounds__(256)
void gemm_nt_kernel(const u16* __restrict__ A, const u16* __restrict__ Btp,
                    u16* __restrict__ out,
                    const float* __restrict__ bias,   // [N]
                    const float* __restrict__ dvec,   // [N]
                    const u16* __restrict__ res,      // [M,N] bf16
                    int M, int N, int K)
{
    __shared__ u16 smem[BM * TPAD];    // 34.8 KB; K-loop uses first 32 KB
    // buf layout: A0 @0, A1 @4096, B0 @8192, B1 @12288 (u16 offsets)
    const int tid  = threadIdx.x;
    const int lane = tid & 63;
    const int wave = tid >> 6;
    const int quad = lane >> 4;
    const int l16  = lane & 15;

    const int NT  = N >> 7;
    const int ntl = (NT == 8) ? 3 : 2;
    const int x    = blockIdx.x & 7;
    const int rest = blockIdx.x >> 3;
    const int n    = rest & (NT - 1);
    const int g    = rest >> ntl;
    const long bm = (long)(g * 8 + x) * BM;
    const long bn = (long)n * BN;

    const int wm = (wave & 1) * 64;
    const int wn = (wave >> 1) * 64;
    const int kblk = K >> 5;   // BK=32 iterations

    floatx4 acc[4][4] = {};

    // A staging (round-3-proven): thread t covers 16B of rows r0 / r0+64
    const int r0 = tid >> 2;
    const int c0 = (tid & 3) * 8;
    const u16* aP = A + (bm + r0) * (long)K + c0;
    // B staging: wave w stages packed n16 blocks {2w, 2w+1} (512 u16 each)
    const u16* b0p = Btp + ((bn >> 4) + 2 * wave)     * (long)kblk * 512 + lane * 8;
    const u16* b1p = Btp + ((bn >> 4) + 2 * wave + 1) * (long)kblk * 512 + lane * 8;

    // prologue: stage tile 0 into buffer 0
    __builtin_amdgcn_global_load_lds((gas_p)(aP),                (las_p)(&smem[tid * 8]),         16, 0, 0);
    __builtin_amdgcn_global_load_lds((gas_p)(aP + 64 * (long)K), (las_p)(&smem[(tid + 256) * 8]), 16, 0, 0);
    __builtin_amdgcn_global_load_lds((gas_p)(b0p), (las_p)(&smem[8192 + (2 * wave) * 512 + lane * 8]),     16, 0, 0);
    __builtin_amdgcn_global_load_lds((gas_p)(b1p), (las_p)(&smem[8192 + (2 * wave + 1) * 512 + lane * 8]), 16, 0, 0);
    __syncthreads();

    for (int ki = 0; ki < kblk; ki++) {
        const int cur = ki & 1;
        if (ki + 1 < kblk) {   // prefetch next tile into alternate buffer
            const int nb = (cur ^ 1) * 4096;
            const u16* ak = aP + (ki + 1) * 32;
            __builtin_amdgcn_global_load_lds((gas_p)(ak),                (las_p)(&smem[nb + tid * 8]),         16, 0, 0);
            __builtin_amdgcn_global_load_lds((gas_p)(ak + 64 * (long)K), (las_p)(&smem[nb + (tid + 256) * 8]), 16, 0, 0);
            __builtin_amdgcn_global_load_lds((gas_p)(b0p + (ki + 1) * 512),
                                             (las_p)(&smem[8192 + nb + (2 * wave) * 512 + lane * 8]), 16, 0, 0);
            __builtin_amdgcn_global_load_lds((gas_p)(b1p + (ki + 1) * 512),
                                             (las_p)(&smem[8192 + nb + (2 * wave + 1) * 512 + lane * 8]), 16, 0, 0);
        }
        const int ab = cur * 4096, bb = 8192 + cur * 4096;
        short8 afr[4], bfr[4];
        #pragma unroll
        for (int mm = 0; mm < 4; mm++)
            afr[mm] = *reinterpret_cast<const short8*>(
                &smem[ab + (wm + mm * 16 + l16) * 32 + quad * 8]);
        #pragma unroll
        for (int nn = 0; nn < 4; nn++)
            bfr[nn] = *reinterpret_cast<const short8*>(
                &smem[bb + ((wn >> 4) + nn) * 512 + lane * 8]);
        #pragma unroll
        for (int mm = 0; mm < 4; mm++)
            #pragma unroll
            for (int nn = 0; nn < 4; nn++)
                acc[mm][nn] = __builtin_amdgcn_mfma_f32_16x16x32_bf16(afr[mm], bfr[nn], acc[mm][nn], 0, 0, 0);
        __syncthreads();   // all waves done reading cur; prefetch landed
    }

    // ---- epilogue: transpose acc through LDS (bf16), then coalesced short8 I/O ----
    // C/D map: col=lane&15, row=quad*4+r (m89-verified)
    #pragma unroll
    for (int mm = 0; mm < 4; mm++)
        #pragma unroll
        for (int nn = 0; nn < 4; nn++)
            #pragma unroll
            for (int r = 0; r < 4; r++)
                smem[(wm + mm * 16 + quad * 4 + r) * TPAD + wn + nn * 16 + l16] =
                    f2bf(acc[mm][nn][r]);
    __syncthreads();

    #pragma unroll
    for (int i = 0; i < 8; i++) {
        const int row = wave * 8 + (lane >> 3) + (i & 3) * 32;
        const int cs  = (lane & 7) + (i >> 2) * 8;
        const long gcol = bn + cs * 8;
        const long off  = (bm + row) * (long)N + gcol;
        short8 v8 = *reinterpret_cast<const short8*>(&smem[row * TPAD + cs * 8]);
        float v[8];
        #pragma unroll
        for (int j = 0; j < 8; j++) v[j] = bf2f((u16)v8[j]);
        if (EPI == EPI_BIAS || EPI == EPI_BIAS_GELU || EPI == EPI_BIAS_RES) {
            float4 bv0 = *reinterpret_cast<const float4*>(&bias[gcol]);
            float4 bv1 = *reinterpret_cast<const float4*>(&bias[gcol + 4]);
            v[0] += bv0.x; v[1] += bv0.y; v[2] += bv0.z; v[3] += bv0.w;
            v[4] += bv1.x; v[5] += bv1.y; v[6] += bv1.z; v[7] += bv1.w;
        }
        if (EPI == EPI_BIAS_GELU) {
            #pragma unroll
            for (int j = 0; j < 8; j++) v[j] = gelu_f(v[j]);
        }
        if (EPI == EPI_DU_GELU_RES) {
            float4 dv0 = *reinterpret_cast<const float4*>(&dvec[gcol]);
            float4 dv1 = *reinterpret_cast<const float4*>(&dvec[gcol + 4]);
            float dv[8] = {dv0.x, dv0.y, dv0.z, dv0.w, dv1.x, dv1.y, dv1.z, dv1.w};
            short8 r8 = *reinterpret_cast<const short8*>(&res[off]);
            #pragma unroll
            for (int j = 0; j < 8; j++) {
                float uv = bf2f((u16)r8[j]);
                v[j] = uv + gelu_f(v[j] + dv[j] * uv);
            }
        }
        if (EPI == EPI_BIAS_RES) {
            short8 r8 = *reinterpret_cast<const short8*>(&res[off]);
            #pragma unroll
            for (int j = 0; j < 8; j++) v[j] += bf2f((u16)r8[j]);
        }
        short8 o;
        #pragma unroll
        for (int j = 0; j < 8; j++) o[j] = (short)f2bf(v[j]);
        *reinterpret_cast<short8*>(&out[off]) = o;
    }
}

// ---------- reset mask ----------
__global__ void reset_kernel(const int* __restrict__ seq, unsigned char* __restrict__ rst) {
    int i = blockIdx.x * 256 + threadIdx.x;      // [0, B*L)
    int l = i & (L_ - 1);
    int cur = seq[i];
    int prev = (l == 0) ? 0 : seq[i - 1];
    rst[i] = (cur != prev) ? 1 : 0;
}

// ---------- lam_bar ----------
__global__ void lamb_kernel(const float* __restrict__ lam_re, const float* __restrict__ lam_im,
                            const float* __restrict__ log_dt, float* __restrict__ lamb) {
    int i = blockIdx.x * 256 + threadIdx.x;      // DEPTH*P
    if (i >= DEPTH_ * P_) return;
    float lr = fminf(lam_re[i], -1e-4f);
    float li = lam_im[i];
    float dt = expf(log_dt[i]);
    float e  = expf(lr * dt);
    lamb[i * 2]     = e * cosf(li * dt);
    lamb[i * 2 + 1] = e * sinf(li * dt);
}

// ---------- W_bu (fragment-major packed): rows p -> Bu_re, 256+p -> Bu_im ----------
__global__ void wbu_kernel(const float* __restrict__ lam_re, const float* __restrict__ lam_im,
                           const float* __restrict__ lamb,
                           const float* __restrict__ B_re, const float* __restrict__ B_im,
                           u16* __restrict__ wbu) {
    long i = (long)blockIdx.x * 256 + threadIdx.x;   // DEPTH*P*H
    int h = (int)(i % H_);
    int p = (int)((i / H_) % P_);
    int l = (int)(i / ((long)H_ * P_));
    int lp = l * P_ + p;
    float lr = fminf(lam_re[lp], -1e-4f), li = lam_im[lp];
    float lbr = lamb[lp * 2], lbi = lamb[lp * 2 + 1];
    float den = lr * lr + li * li;
    float fr = ((lbr - 1.0f) * lr + lbi * li) / den;
    float fi = (lbi * lr - (lbr - 1.0f) * li) / den;
    float Br = B_re[(long)lp * H_ + h], Bi = B_im[(long)lp * H_ + h];
    long base = (long)l * 512 * 512;
    wbu[base + dst_off(p, h, 512)]       = f2bf(fr * Br - fi * Bi);
    wbu[base + dst_off(256 + p, h, 512)] = f2bf(fr * Bi + fi * Br);
}

// ---------- W_c = [C_re | -C_im], fragment-major packed: n=h, k in [0,512) ----------
__global__ void wc_kernel(const float* __restrict__ C_re, const float* __restrict__ C_im,
                          u16* __restrict__ wc) {
    long i = (long)blockIdx.x * 256 + threadIdx.x;   // DEPTH*H*512
    int k = (int)(i % 512);
    int h = (int)((i / 512) % H_);
    int l = (int)(i / (512L * H_));
    float v = (k < 256) ? C_re[((long)l * H_ + h) * P_ + k]
                        : -C_im[((long)l * H_ + h) * P_ + (k - 256)];
    wc[(long)l * 512 * 512 + dst_off(h, k, 512)] = f2bf(v);
}

// ---------- pack fp32 [batch][K][N] -> bf16 fragment-major [batch][dst_off(n,k,K)] ----------
__global__ void pack_bt_kernel(const float* __restrict__ src, u16* __restrict__ dst,
                               int K, int N, long total) {
    long i = (long)blockIdx.x * 256 + threadIdx.x;
    if (i >= total) return;
    long kn = (long)K * N;
    int b = (int)(i / kn);
    long rem = i - (long)b * kn;
    int k = (int)(rem / N), n = (int)(rem % N);
    dst[(long)b * kn + dst_off(n, k, K)] = f2bf(src[i]);
}

// ---------- FiLM scale/shift from (difficulty, fav) ----------
__global__ void modk_kernel(const float* __restrict__ diffr, const float* __restrict__ favs,
                            const float* __restrict__ sW, const float* __restrict__ sb,
                            const float* __restrict__ scW, const float* __restrict__ scb,
                            float* __restrict__ shift_all, float* __restrict__ scale_all) {
    int i = blockIdx.x * 256 + threadIdx.x;          // DEPTH*B*H
    int h = i % H_;
    int b = (i / H_) % B_;
    int l = i / (H_ * B_);
    float r0 = diffr[b], r1 = favs[b];
    float sh = r0 * sW[(l * 2 + 0) * H_ + h] + r1 * sW[(l * 2 + 1) * H_ + h] + sb[l * H_ + h];
    float sc = r0 * scW[(l * 2 + 0) * H_ + h] + r1 * scW[(l * 2 + 1) * H_ + h] + scb[l * H_ + h];
    bool even = (h & 1) == 0;
    shift_all[i] = even ? cosf(sh) : sinf(sh);
    scale_all[i] = even ? cosf(sc) : sinf(sc);
}

// ---------- layernorm (no affine) of fp32 audio -> bf16 ----------
__global__ __launch_bounds__(256)
void ln_audio_kernel(const float* __restrict__ x, u16* __restrict__ out) {
    int wave = threadIdx.x >> 6, lane = threadIdx.x & 63;
    long row = (long)blockIdx.x * 4 + wave;
    const float* xr = x + row * F_ + lane * 8;
    float4 p0 = *reinterpret_cast<const float4*>(xr);
    float4 p1 = *reinterpret_cast<const float4*>(xr + 4);
    float v[8] = {p0.x, p0.y, p0.z, p0.w, p1.x, p1.y, p1.z, p1.w};
    float s = 0.f, s2 = 0.f;
    #pragma unroll
    for (int j = 0; j < 8; j++) { s += v[j]; s2 += v[j] * v[j]; }
    for (int d = 32; d; d >>= 1) { s += __shfl_xor(s, d); s2 += __shfl_xor(s2, d); }
    float mean = s * (1.0f / F_);
    float var  = s2 * (1.0f / F_) - mean * mean;
    float rs = rsqrtf(var + EPS_);
    short8 o;
    #pragma unroll
    for (int j = 0; j < 8; j++) o[j] = (short)f2bf((v[j] - mean) * rs);
    *reinterpret_cast<short8*>(out + row * F_ + lane * 8) = o;
}

// ---------- u = std(s) * scale[b] + shift[b], bf16 in/out ----------
__global__ __launch_bounds__(256)
void ln_scale_kernel(const u16* __restrict__ sin_, const float* __restrict__ scale,
                     const float* __restrict__ shift, u16* __restrict__ out) {
    int wave = threadIdx.x >> 6, lane = threadIdx.x & 63;
    long row = (long)blockIdx.x * 4 + wave;
    int b = (int)(row >> 12);    // row / L_
    short8 xv = *reinterpret_cast<const short8*>(sin_ + row * H_ + lane * 8);
    float v[8];
    #pragma unroll
    for (int j = 0; j < 8; j++) v[j] = bf2f((u16)xv[j]);
    float s = 0.f, s2 = 0.f;
    #pragma unroll
    for (int j = 0; j < 8; j++) { s += v[j]; s2 += v[j] * v[j]; }
    for (int d = 32; d; d >>= 1) { s += __shfl_xor(s, d); s2 += __shfl_xor(s2, d); }
    float mean = s * (1.0f / H_);
    float var  = s2 * (1.0f / H_) - mean * mean;
    float rs = rsqrtf(var + EPS_);
    short8 o;
    #pragma unroll
    for (int j = 0; j < 8; j++) {
        int h = lane * 8 + j;
        o[j] = (short)f2bf((v[j] - mean) * rs * scale[b * H_ + h] + shift[b * H_ + h]);
    }
    *reinterpret_cast<short8*>(out + row * H_ + lane * 8) = o;
}

// ---------- scan: x[t] = a[t]*x[t-1] + Bu[t], a = reset ? 0 : lam_bar ----------
__global__ __launch_bounds__(256)
void scan_phase1(const u16* __restrict__ bu, const unsigned char* __restrict__ reset,
                 const float* __restrict__ lamb, float2* __restrict__ Achunk,
                 float2* __restrict__ xlast) {
    int p = threadIdx.x;
    int c = blockIdx.x & (NCH - 1);
    int b = blockIdx.x >> 7;            // NCH == 128
    float lbr = lamb[p * 2], lbi = lamb[p * 2 + 1];
    float xr = 0.f, xi = 0.f, Ar = 1.f, Ai = 0.f;
    long base = (long)b * L_ + c * CLEN;
    for (int i = 0; i < CLEN; i++) {
        long l = base + i;
        float br = bf2f(bu[l * 512 + p]);
        float bi = bf2f(bu[l * 512 + 256 + p]);
        bool r = reset[l] != 0;
        float ar = r ? 0.f : lbr, ai = r ? 0.f : lbi;
        float nxr = ar * xr - ai * xi + br;
        float nxi = ar * xi + ai * xr + bi;
        float nAr = ar * Ar - ai * Ai;
        float nAi = ar * Ai + ai * Ar;
        xr = nxr; xi = nxi; Ar = nAr; Ai = nAi;
    }
    long ci = ((long)b * NCH + c) * 256 + p;
    Achunk[ci] = make_float2(Ar, Ai);
    xlast[ci]  = make_float2(xr, xi);
}

// phase3 with inline lookback (replaces separate phase2 dispatch):
// carry for chunk c = fold over chunks 0..c-1 of (A, xlast).
// Runs IN-PLACE on bu (each element read once then overwritten by same thread).
__global__ __launch_bounds__(256)
void scan_phase3(u16* __restrict__ bu, const unsigned char* __restrict__ reset,
                 const float* __restrict__ lamb,
                 const float2* __restrict__ Achunk, const float2* __restrict__ xlast) {
    int p = threadIdx.x;
    int c = blockIdx.x & (NCH - 1);
    int b = blockIdx.x >> 7;
    float lbr = lamb[p * 2], lbi = lamb[p * 2 + 1];
    float cr = 0.f, ci = 0.f;
    long cbase = ((long)b * NCH) * 256 + p;
    for (int cc = 0; cc < c; cc++) {
        float2 Aa = Achunk[cbase + (long)cc * 256];
        float2 xl = xlast[cbase + (long)cc * 256];
        float nr = Aa.x * cr - Aa.y * ci + xl.x;
        float ni = Aa.x * ci + Aa.y * cr + xl.y;
        cr = nr; ci = ni;
    }
    float xr = cr, xi = ci;
    long base = (long)b * L_ + c * CLEN;
    for (int i = 0; i < CLEN; i++) {
        long l = base + i;
        float br = bf2f(bu[l * 512 + p]);
        float bi = bf2f(bu[l * 512 + 256 + p]);
        bool r = reset[l] != 0;
        float ar = r ? 0.f : lbr, ai = r ? 0.f : lbi;
        float nxr = ar * xr - ai * xi + br;
        float nxi = ar * xi + ai * xr + bi;
        xr = nxr; xi = nxi;
        bu[l * 512 + p]       = f2bf(xr);
        bu[l * 512 + 256 + p] = f2bf(xi);
    }
}

// ---------- heads weight pack: fragment-major headWf[16384] bf16 + headb[32] ----------
__global__ void pack_heads_kernel(const float* __restrict__ diff_W, const float* __restrict__ diff_b,
                                  const float* __restrict__ hit_W, const float* __restrict__ hit_b,
                                  const float* __restrict__ slider_W, const float* __restrict__ slider_b,
                                  const float* __restrict__ pos_W, const float* __restrict__ pos_b,
                                  const float* __restrict__ scal_W, const float* __restrict__ scal_b,
                                  u16* __restrict__ headWf, float* __restrict__ headb) {
    int i = blockIdx.x * 256 + threadIdx.x;   // 16384
    int ks = i >> 10;
    int r1 = i & 1023;
    int n16 = r1 >> 9;
    int r2 = r1 & 511;
    int ln = r2 >> 3;
    int j = r2 & 7;
    int kseg = ln >> 4, row = ln & 15;
    int n = n16 * 16 + row;
    int k = ks * 32 + kseg * 8 + j;
    float v = 0.f;
    if (n < 4)       v = diff_W[k * 4 + n];
    else if (n < 8)  v = hit_W[k * 4 + (n - 4)];
    else if (n < 12) v = slider_W[k * 4 + (n - 8)];
    else if (n < 14) v = pos_W[k * 2 + (n - 12)];
    else if (n < 18) v = scal_W[k * 4 + (n - 14)];
    headWf[i] = f2bf(v);
    if (i < 32) {
        float b = 0.f;
        if (i < 4)       b = diff_b[i];
        else if (i < 8)  b = hit_b[i - 4];
        else if (i < 12) b = slider_b[i - 8];
        else if (i < 14) b = pos_b[i - 12];
        else if (i < 18) b = scal_b[i - 14];
        headb[i] = b;
    }
}

// ---------- heads MFMA GEMM: out-scatter of u[M,512] @ headW[32,512]^T ----------
__global__ __launch_bounds__(256)
void heads_mfma_kernel(const u16* __restrict__ u, const u16* __restrict__ headWf,
                       const float* __restrict__ headb, float* __restrict__ out) {
    __shared__ u16 lB[16384];   // 32 KB, fragment-major, staged once (flat copy)
    __shared__ u16 lA[4096];    // 8 KB, row-major [128][32]
    const int tid  = threadIdx.x;
    const int lane = tid & 63;
    const int wave = tid >> 6;
    const int quad = lane >> 4;
    const int l16  = lane & 15;
    const long bm = (long)blockIdx.x * 128;

    #pragma unroll
    for (int t = 0; t < 8; t++) {
        int blk = wave * 8 + t;
        __builtin_amdgcn_global_load_lds((gas_p)(headWf + blk * 512 + lane * 8),
                                         (las_p)(&lB[blk * 512 + lane * 8]), 16, 0, 0);
    }

    floatx4 acc[2][2] = {};
    const int r0 = tid >> 2;
    const int c0 = (tid & 3) * 8;
    const u16* a0 = u + (bm + r0)      * 512L + c0;
    const u16* a1 = u + (bm + r0 + 64) * 512L + c0;

    for (int ks = 0; ks < 16; ks++) {
        __builtin_amdgcn_global_load_lds((gas_p)(a0 + ks * 32), (las_p)(&lA[tid * 8]),         16, 0, 0);
        __builtin_amdgcn_global_load_lds((gas_p)(a1 + ks * 32), (las_p)(&lA[(tid + 256) * 8]), 16, 0, 0);
        __syncthreads();
        short8 afr[2], bfr[2];
        #pragma unroll
        for (int mm = 0; mm < 2; mm++)
            afr[mm] = *reinterpret_cast<const short8*>(&lA[(wave * 32 + mm * 16 + l16) * 32 + quad * 8]);
        #pragma unroll
        for (int nn = 0; nn < 2; nn++)
            bfr[nn] = *reinterpret_cast<const short8*>(&lB[ks * 1024 + nn * 512 + lane * 8]);
        #pragma unroll
        for (int mm = 0; mm < 2; mm++)
            #pragma unroll
            for (int nn = 0; nn < 2; nn++)
                acc[mm][nn] = __builtin_amdgcn_mfma_f32_16x16x32_bf16(afr[mm], bfr[nn], acc[mm][nn], 0, 0, 0);
        __syncthreads();
    }

    float* pos_o    = out;            // [B,L,2]
    float* combo_o  = out + 65536;    // [B,L]
    float* curve_o  = out + 98304;
    float* timing_o = out + 131072;
    float* rep_o    = out + 163840;
    float* hit_o    = out + 196608;   // [B,L,4]
    float* slider_o = out + 327680;
    float* diff_o   = out + 458752;

    #pragma unroll
    for (int nn = 0; nn < 2; nn++) {
        const int col = nn * 16 + l16;
        if (col >= 18) continue;
        const float bv = headb[col];
        #pragma unroll
        for (int mm = 0; mm < 2; mm++) {
            #pragma unroll
            for (int r = 0; r < 4; r++) {
                const long row = bm + wave * 32 + mm * 16 + quad * 4 + r;
                float v = acc[mm][nn][r] + bv;
                if (col < 4)       diff_o[row * 4 + col] = tanh_f(v);
                else if (col < 8)  hit_o[row * 4 + (col - 4)] = v;
                else if (col < 12) slider_o[row * 4 + (col - 8)] = v;
                else if (col < 14) pos_o[row * 2 + (col - 12)] = tanh_f(v);
                else if (col == 14) timing_o[row] = v;
                else if (col == 15) combo_o[row] = v;
                else if (col == 16) curve_o[row] = v;
                else                rep_o[row] = __builtin_amdgcn_exp2f(fmaxf(v, 0.0f));
            }
        }
    }
}

// =======================================================================
extern "C" void kernel_launch(void* const* d_in, const int* in_sizes, int n_in,
                              void* d_out, int out_size, void* d_ws, size_t ws_size,
                              hipStream_t stream) {
    const float* raw_audio = (const float*)d_in[0];
    const int*   seq_ids   = (const int*)d_in[1];
    const float* diffr     = (const float*)d_in[2];
    const float* favs      = (const float*)d_in[3];
    const float* in_W      = (const float*)d_in[4];
    const float* in_b      = (const float*)d_in[5];
    const float* shift_W   = (const float*)d_in[6];
    const float* shift_b   = (const float*)d_in[7];
    const float* scale_W   = (const float*)d_in[8];
    const float* scale_b   = (const float*)d_in[9];
    const float* lam_re    = (const float*)d_in[10];
    const float* lam_im    = (const float*)d_in[11];
    const float* log_dt    = (const float*)d_in[12];
    const float* B_re      = (const float*)d_in[13];
    const float* B_im      = (const float*)d_in[14];
    const float* C_re      = (const float*)d_in[15];
    const float* C_im      = (const float*)d_in[16];
    const float* Dp        = (const float*)d_in[17];
    const float* ffn_W1    = (const float*)d_in[18];
    const float* ffn_b1    = (const float*)d_in[19];
    const float* ffn_W2    = (const float*)d_in[20];
    const float* ffn_b2    = (const float*)d_in[21];
    const float* diff_W    = (const float*)d_in[22];
    const float* diff_b    = (const float*)d_in[23];
    const float* hit_W     = (const float*)d_in[24];
    const float* hit_b     = (const float*)d_in[25];
    const float* slider_W  = (const float*)d_in[26];
    const float* slider_b  = (const float*)d_in[27];
    const float* pos_W     = (const float*)d_in[28];
    const float* pos_b     = (const float*)d_in[29];
    const float* scal_W    = (const float*)d_in[30];
    const float* scal_b    = (const float*)d_in[31];

    char* ws = (char*)d_ws;
    size_t off = 0;
    auto alloc = [&](size_t bytes) -> void* {
        void* p = ws + off; off += (bytes + 255) & ~(size_t)255; return p;
    };
    u16* u_b   = (u16*)alloc((size_t)M_ * H_ * 2);
    u16* z_b   = (u16*)alloc((size_t)M_ * H_ * 2);
    u16* bu_b  = (u16*)alloc((size_t)M_ * H_ * 2);
    u16* ff1_b = (u16*)alloc((size_t)M_ * 1024 * 2);
    u16* lnA_b = ff1_b;    // alias: lnA only live before layer 0's FFN1
    u16* x_b   = bu_b;     // alias: scan output in-place over Bu
    u16* s_b   = bu_b;     // alias: FFN2 output reuses Bu slot
    u16* inWT  = (u16*)alloc((size_t)H_ * F_ * 2);
    u16* wbu   = (u16*)alloc((size_t)DEPTH_ * 512 * H_ * 2);
    u16* wc    = (u16*)alloc((size_t)DEPTH_ * H_ * 512 * 2);
    u16* w1t   = (u16*)alloc((size_t)DEPTH_ * 1024 * H_ * 2);
    u16* w2t   = (u16*)alloc((size_t)DEPTH_ * H_ * 1024 * 2);
    float* lamb = (float*)alloc((size_t)DEPTH_ * P_ * 2 * 4);
    unsigned char* rst = (unsigned char*)alloc(M_);
    float* shift_all = (float*)alloc((size_t)DEPTH_ * B_ * H_ * 4);
    float* scale_all = (float*)alloc((size_t)DEPTH_ * B_ * H_ * 4);
    float2* Achunk = (float2*)alloc((size_t)B_ * NCH * P_ * 8);
    float2* xlastc = (float2*)alloc((size_t)B_ * NCH * P_ * 8);
    u16* headWf = (u16*)alloc((size_t)16384 * 2);
    float* headb = (float*)alloc(32 * 4);
    (void)in_sizes; (void)n_in; (void)out_size; (void)ws_size;

    // ---- weight / constant prep ----
    reset_kernel<<<M_ / 256, 256, 0, stream>>>(seq_ids, rst);
    lamb_kernel<<<(DEPTH_ * P_ + 255) / 256, 256, 0, stream>>>(lam_re, lam_im, log_dt, lamb);
    wbu_kernel<<<(DEPTH_ * P_ * H_) / 256, 256, 0, stream>>>(lam_re, lam_im, lamb, B_re, B_im, wbu);
    wc_kernel<<<(DEPTH_ * H_ * 512) / 256, 256, 0, stream>>>(C_re, C_im, wc);
    pack_bt_kernel<<<(F_ * H_) / 256, 256, 0, stream>>>(in_W, inWT, 512, 512, (long)F_ * H_);
    pack_bt_kernel<<<(DEPTH_ * H_ * 1024) / 256, 256, 0, stream>>>(ffn_W1, w1t, 512, 1024,
                                                                   (long)DEPTH_ * H_ * 1024);
    pack_bt_kernel<<<(DEPTH_ * 1024 * H_) / 256, 256, 0, stream>>>(ffn_W2, w2t, 1024, 512,
                                                                   (long)DEPTH_ * 1024 * H_);
    modk_kernel<<<(DEPTH_ * B_ * H_) / 256, 256, 0, stream>>>(diffr, favs, shift_W, shift_b,
                                                              scale_W, scale_b, shift_all, scale_all);
    pack_heads_kernel<<<16384 / 256, 256, 0, stream>>>(diff_W, diff_b, hit_W, hit_b,
                                                       slider_W, slider_b, pos_W, pos_b,
                                                       scal_W, scal_b, headWf, headb);

    // ---- stem: u = std(audio) @ in_W + in_b ----
    ln_audio_kernel<<<M_ / 4, 256, 0, stream>>>(raw_audio, lnA_b);
    const int g512  = (M_ / BM) * (512 / BN);    // 1024 blocks, XCD-swizzled 1D
    const int g1024 = (M_ / BM) * (1024 / BN);   // 2048 blocks
    gemm_nt_kernel<EPI_BIAS><<<g512, 256, 0, stream>>>(lnA_b, inWT, u_b, in_b, nullptr, nullptr,
                                                       M_, H_, F_);

    // ---- layers ----
    for (int l = 0; l < DEPTH_; l++) {
        gemm_nt_kernel<EPI_STORE><<<g512, 256, 0, stream>>>(u_b, wbu + (size_t)l * 512 * H_, bu_b,
                                                            nullptr, nullptr, nullptr, M_, 512, H_);
        scan_phase1<<<B_ * NCH, 256, 0, stream>>>(bu_b, rst, lamb + l * P_ * 2, Achunk, xlastc);
        scan_phase3<<<B_ * NCH, 256, 0, stream>>>(bu_b, rst, lamb + l * P_ * 2, Achunk, xlastc);
        gemm_nt_kernel<EPI_DU_GELU_RES><<<g512, 256, 0, stream>>>(x_b, wc + (size_t)l * H_ * 512, z_b,
                                                                  nullptr, Dp + (size_t)l * H_, u_b,
                                                                  M_, H_, 512);
        gemm_nt_kernel<EPI_BIAS_GELU><<<g1024, 256, 0, stream>>>(z_b, w1t + (size_t)l * 1024 * H_, ff1_b,
                                                                 ffn_b1 + (size_t)l * 1024, nullptr, nullptr,
                                                                 M_, 1024, H_);
        gemm_nt_kernel<EPI_BIAS_RES><<<g512, 256, 0, stream>>>(ff1_b, w2t + (size_t)l * H_ * 1024, s_b,
                                                               ffn_b2 + (size_t)l * H_, nullptr, z_b,
                                                               M_, H_, 1024);
        ln_scale_kernel<<<M_ / 4, 256, 0, stream>>>(s_b, scale_all + (size_t)l * B_ * H_,
                                                    shift_all + (size_t)l * B_ * H_, u_b);
    }

    // ---- heads ----
    heads_mfma_kernel<<<M_ / 128, 256, 0, stream>>>(u_b, headWf, headb, (float*)d_out);
}

// Round 9
// 1473.628 us; speedup vs baseline: 1.1166x; 1.1166x over previous
//
#include <hip/hip_runtime.h>
#include <hip/hip_bf16.h>
#include <math.h>

// Problem dims
#define B_ 8
#define L_ 4096
#define F_ 512
#define H_ 512
#define P_ 256
#define DEPTH_ 6
#define M_ (B_*L_)      // 32768 rows
#define EPS_ 1e-5f

// scan chunking
#define NCH 128
#define CLEN 32         // NCH*CLEN == L_

typedef unsigned short u16;
typedef short short8 __attribute__((ext_vector_type(8)));
typedef float floatx4 __attribute__((ext_vector_type(4)));

typedef const __attribute__((address_space(1))) unsigned short* gas_p;
typedef __attribute__((address_space(3))) unsigned short* las_p;

// ---------- bf16 helpers (bit-level, header-proof) ----------
__device__ __forceinline__ u16 f2bf(float x) {
    union { float f; unsigned int u; } v; v.f = x;
    unsigned int u = v.u;
    unsigned int lsb = (u >> 16) & 1u;
    u += 0x7fffu + lsb;           // round-to-nearest-even
    return (u16)(u >> 16);
}
__device__ __forceinline__ float bf2f(u16 s) {
    union { unsigned int u; float f; } v; v.u = ((unsigned int)s) << 16;
    return v.f;
}
// fast gelu (tanh form, HW exp2/rcp)
__device__ __forceinline__ float gelu_f(float x) {
    float inner = x * (1.0f + 0.044715f * x * x);
    float e = __builtin_amdgcn_exp2f(2.3022083f * inner);
    float r = __builtin_amdgcn_rcpf(1.0f + e);
    return x - x * r;
}
// fast tanh
__device__ __forceinline__ float tanh_f(float y) {
    float e = __builtin_amdgcn_exp2f(2.88539008f * y);
    float r = __builtin_amdgcn_rcpf(1.0f + e);
    return 1.0f - 2.0f * r;
}

// fragment-major packed offset for weight Bt[n][k] (K = reduction dim):
// block (n16 = n/16, ks = k/32) -> 512 contiguous u16; inside:
// kseg=(k>>3)&3, row=n&15, j=k&7 -> kseg*128 + row*8 + j
__device__ __forceinline__ long dst_off(int n, int k, int K) {
    return ((long)((n >> 4) * (K >> 5) + (k >> 5))) * 512
         + ((k >> 3) & 3) * 128 + (n & 15) * 8 + (k & 7);
}

// ---------- GEMM: C[M,N] = A[M,K] @ Bt_packed, bf16 in, fp32 acc, bf16 out ----------
#define BM 128
#define BN 128
#define TPAD 136   // epilogue transpose row stride (u16): 272 B, 16B-aligned

enum { EPI_STORE = 0, EPI_BIAS = 1, EPI_BIAS_GELU = 2, EPI_DU_GELU_RES = 3, EPI_BIAS_RES = 4 };

// Grid: 1D, XCD-swizzled: id = 8*NT*g + 8*n + x, m-tile = 8g+x -> all N-tiles
// of an M-tile share id%8 (same XCD) -> A fetched into one L2 only.
// K-loop: BK=32, double-buffered LDS (2x16KB), prefetch next tile BEFORE
// computing current, ONE barrier per iter -> drain waits (latency - compute)
// instead of full load latency.  [round-8-proven: 68 -> 54.7 us on FFN shape]
template<int EPI>
__global__ __launch_bounds__(256)
void gemm_nt_kernel(const u16* __restrict__ A, const u16* __restrict__ Btp,
                    u16* __restrict__ out,
                    const float* __restrict__ bias,   // [N]
                    const float* __restrict__ dvec,   // [N]
                    const u16* __restrict__ res,      // [M,N] bf16
                    int M, int N, int K)
{
    __shared__ u16 smem[BM * TPAD];    // 34.8 KB; K-loop uses first 32 KB
    // buf layout: A0 @0, A1 @4096, B0 @8192, B1 @12288 (u16 offsets)
    const int tid  = threadIdx.x;
    const int lane = tid & 63;
    const int wave = tid >> 6;
    const int quad = lane >> 4;
    const int l16  = lane & 15;

    const int NT  = N >> 7;
    const int ntl = (NT == 8) ? 3 : 2;
    const int x    = blockIdx.x & 7;
    const int rest = blockIdx.x >> 3;
    const int n    = rest & (NT - 1);
    const int g    = rest >> ntl;
    const long bm = (long)(g * 8 + x) * BM;
    const long bn = (long)n * BN;

    const int wm = (wave & 1) * 64;
    const int wn = (wave >> 1) * 64;
    const int kblk = K >> 5;   // BK=32 iterations

    floatx4 acc[4][4] = {};

    // A staging (round-3-proven): thread t covers 16B of rows r0 / r0+64
    const int r0 = tid >> 2;
    const int c0 = (tid & 3) * 8;
    const u16* aP = A + (bm + r0) * (long)K + c0;
    // B staging: wave w stages packed n16 blocks {2w, 2w+1} (512 u16 each)
    const u16* b0p = Btp + ((bn >> 4) + 2 * wave)     * (long)kblk * 512 + lane * 8;
    const u16* b1p = Btp + ((bn >> 4) + 2 * wave + 1) * (long)kblk * 512 + lane * 8;

    // prologue: stage tile 0 into buffer 0
    __builtin_amdgcn_global_load_lds((gas_p)(aP),                (las_p)(&smem[tid * 8]),         16, 0, 0);
    __builtin_amdgcn_global_load_lds((gas_p)(aP + 64 * (long)K), (las_p)(&smem[(tid + 256) * 8]), 16, 0, 0);
    __builtin_amdgcn_global_load_lds((gas_p)(b0p), (las_p)(&smem[8192 + (2 * wave) * 512 + lane * 8]),     16, 0, 0);
    __builtin_amdgcn_global_load_lds((gas_p)(b1p), (las_p)(&smem[8192 + (2 * wave + 1) * 512 + lane * 8]), 16, 0, 0);
    __syncthreads();

    for (int ki = 0; ki < kblk; ki++) {
        const int cur = ki & 1;
        if (ki + 1 < kblk) {   // prefetch next tile into alternate buffer
            const int nb = (cur ^ 1) * 4096;
            const u16* ak = aP + (ki + 1) * 32;
            __builtin_amdgcn_global_load_lds((gas_p)(ak),                (las_p)(&smem[nb + tid * 8]),         16, 0, 0);
            __builtin_amdgcn_global_load_lds((gas_p)(ak + 64 * (long)K), (las_p)(&smem[nb + (tid + 256) * 8]), 16, 0, 0);
            __builtin_amdgcn_global_load_lds((gas_p)(b0p + (ki + 1) * 512),
                                             (las_p)(&smem[8192 + nb + (2 * wave) * 512 + lane * 8]), 16, 0, 0);
            __builtin_amdgcn_global_load_lds((gas_p)(b1p + (ki + 1) * 512),
                                             (las_p)(&smem[8192 + nb + (2 * wave + 1) * 512 + lane * 8]), 16, 0, 0);
        }
        const int ab = cur * 4096, bb = 8192 + cur * 4096;
        short8 afr[4], bfr[4];
        #pragma unroll
        for (int mm = 0; mm < 4; mm++)
            afr[mm] = *reinterpret_cast<const short8*>(
                &smem[ab + (wm + mm * 16 + l16) * 32 + quad * 8]);
        #pragma unroll
        for (int nn = 0; nn < 4; nn++)
            bfr[nn] = *reinterpret_cast<const short8*>(
                &smem[bb + ((wn >> 4) + nn) * 512 + lane * 8]);
        #pragma unroll
        for (int mm = 0; mm < 4; mm++)
            #pragma unroll
            for (int nn = 0; nn < 4; nn++)
                acc[mm][nn] = __builtin_amdgcn_mfma_f32_16x16x32_bf16(afr[mm], bfr[nn], acc[mm][nn], 0, 0, 0);
        __syncthreads();   // all waves done reading cur; prefetch landed
    }

    // ---- epilogue: transpose acc through LDS (bf16), then coalesced short8 I/O ----
    // C/D map: col=lane&15, row=quad*4+r (m89-verified)
    #pragma unroll
    for (int mm = 0; mm < 4; mm++)
        #pragma unroll
        for (int nn = 0; nn < 4; nn++)
            #pragma unroll
            for (int r = 0; r < 4; r++)
                smem[(wm + mm * 16 + quad * 4 + r) * TPAD + wn + nn * 16 + l16] =
                    f2bf(acc[mm][nn][r]);
    __syncthreads();

    #pragma unroll
    for (int i = 0; i < 8; i++) {
        const int row = wave * 8 + (lane >> 3) + (i & 3) * 32;
        const int cs  = (lane & 7) + (i >> 2) * 8;
        const long gcol = bn + cs * 8;
        const long off  = (bm + row) * (long)N + gcol;
        short8 v8 = *reinterpret_cast<const short8*>(&smem[row * TPAD + cs * 8]);
        float v[8];
        #pragma unroll
        for (int j = 0; j < 8; j++) v[j] = bf2f((u16)v8[j]);
        if (EPI == EPI_BIAS || EPI == EPI_BIAS_GELU || EPI == EPI_BIAS_RES) {
            float4 bv0 = *reinterpret_cast<const float4*>(&bias[gcol]);
            float4 bv1 = *reinterpret_cast<const float4*>(&bias[gcol + 4]);
            v[0] += bv0.x; v[1] += bv0.y; v[2] += bv0.z; v[3] += bv0.w;
            v[4] += bv1.x; v[5] += bv1.y; v[6] += bv1.z; v[7] += bv1.w;
        }
        if (EPI == EPI_BIAS_GELU) {
            #pragma unroll
            for (int j = 0; j < 8; j++) v[j] = gelu_f(v[j]);
        }
        if (EPI == EPI_DU_GELU_RES) {
            float4 dv0 = *reinterpret_cast<const float4*>(&dvec[gcol]);
            float4 dv1 = *reinterpret_cast<const float4*>(&dvec[gcol + 4]);
            float dv[8] = {dv0.x, dv0.y, dv0.z, dv0.w, dv1.x, dv1.y, dv1.z, dv1.w};
            short8 r8 = *reinterpret_cast<const short8*>(&res[off]);
            #pragma unroll
            for (int j = 0; j < 8; j++) {
                float uv = bf2f((u16)r8[j]);
                v[j] = uv + gelu_f(v[j] + dv[j] * uv);
            }
        }
        if (EPI == EPI_BIAS_RES) {
            short8 r8 = *reinterpret_cast<const short8*>(&res[off]);
            #pragma unroll
            for (int j = 0; j < 8; j++) v[j] += bf2f((u16)r8[j]);
        }
        short8 o;
        #pragma unroll
        for (int j = 0; j < 8; j++) o[j] = (short)f2bf(v[j]);
        *reinterpret_cast<short8*>(&out[off]) = o;
    }
}

// ---------- reset mask ----------
__global__ void reset_kernel(const int* __restrict__ seq, unsigned char* __restrict__ rst) {
    int i = blockIdx.x * 256 + threadIdx.x;      // [0, B*L)
    int l = i & (L_ - 1);
    int cur = seq[i];
    int prev = (l == 0) ? 0 : seq[i - 1];
    rst[i] = (cur != prev) ? 1 : 0;
}

// ---------- lam_bar ----------
__global__ void lamb_kernel(const float* __restrict__ lam_re, const float* __restrict__ lam_im,
                            const float* __restrict__ log_dt, float* __restrict__ lamb) {
    int i = blockIdx.x * 256 + threadIdx.x;      // DEPTH*P
    if (i >= DEPTH_ * P_) return;
    float lr = fminf(lam_re[i], -1e-4f);
    float li = lam_im[i];
    float dt = expf(log_dt[i]);
    float e  = expf(lr * dt);
    lamb[i * 2]     = e * cosf(li * dt);
    lamb[i * 2 + 1] = e * sinf(li * dt);
}

// ---------- W_bu (fragment-major packed): rows p -> Bu_re, 256+p -> Bu_im ----------
__global__ void wbu_kernel(const float* __restrict__ lam_re, const float* __restrict__ lam_im,
                           const float* __restrict__ lamb,
                           const float* __restrict__ B_re, const float* __restrict__ B_im,
                           u16* __restrict__ wbu) {
    long i = (long)blockIdx.x * 256 + threadIdx.x;   // DEPTH*P*H
    int h = (int)(i % H_);
    int p = (int)((i / H_) % P_);
    int l = (int)(i / ((long)H_ * P_));
    int lp = l * P_ + p;
    float lr = fminf(lam_re[lp], -1e-4f), li = lam_im[lp];
    float lbr = lamb[lp * 2], lbi = lamb[lp * 2 + 1];
    float den = lr * lr + li * li;
    float fr = ((lbr - 1.0f) * lr + lbi * li) / den;
    float fi = (lbi * lr - (lbr - 1.0f) * li) / den;
    float Br = B_re[(long)lp * H_ + h], Bi = B_im[(long)lp * H_ + h];
    long base = (long)l * 512 * 512;
    wbu[base + dst_off(p, h, 512)]       = f2bf(fr * Br - fi * Bi);
    wbu[base + dst_off(256 + p, h, 512)] = f2bf(fr * Bi + fi * Br);
}

// ---------- W_c = [C_re | -C_im], fragment-major packed: n=h, k in [0,512) ----------
__global__ void wc_kernel(const float* __restrict__ C_re, const float* __restrict__ C_im,
                          u16* __restrict__ wc) {
    long i = (long)blockIdx.x * 256 + threadIdx.x;   // DEPTH*H*512
    int k = (int)(i % 512);
    int h = (int)((i / 512) % H_);
    int l = (int)(i / (512L * H_));
    float v = (k < 256) ? C_re[((long)l * H_ + h) * P_ + k]
                        : -C_im[((long)l * H_ + h) * P_ + (k - 256)];
    wc[(long)l * 512 * 512 + dst_off(h, k, 512)] = f2bf(v);
}

// ---------- pack fp32 [batch][K][N] -> bf16 fragment-major [batch][dst_off(n,k,K)] ----------
__global__ void pack_bt_kernel(const float* __restrict__ src, u16* __restrict__ dst,
                               int K, int N, long total) {
    long i = (long)blockIdx.x * 256 + threadIdx.x;
    if (i >= total) return;
    long kn = (long)K * N;
    int b = (int)(i / kn);
    long rem = i - (long)b * kn;
    int k = (int)(rem / N), n = (int)(rem % N);
    dst[(long)b * kn + dst_off(n, k, K)] = f2bf(src[i]);
}

// ---------- FiLM scale/shift from (difficulty, fav) ----------
__global__ void modk_kernel(const float* __restrict__ diffr, const float* __restrict__ favs,
                            const float* __restrict__ sW, const float* __restrict__ sb,
                            const float* __restrict__ scW, const float* __restrict__ scb,
                            float* __restrict__ shift_all, float* __restrict__ scale_all) {
    int i = blockIdx.x * 256 + threadIdx.x;          // DEPTH*B*H
    int h = i % H_;
    int b = (i / H_) % B_;
    int l = i / (H_ * B_);
    float r0 = diffr[b], r1 = favs[b];
    float sh = r0 * sW[(l * 2 + 0) * H_ + h] + r1 * sW[(l * 2 + 1) * H_ + h] + sb[l * H_ + h];
    float sc = r0 * scW[(l * 2 + 0) * H_ + h] + r1 * scW[(l * 2 + 1) * H_ + h] + scb[l * H_ + h];
    bool even = (h & 1) == 0;
    shift_all[i] = even ? cosf(sh) : sinf(sh);
    scale_all[i] = even ? cosf(sc) : sinf(sc);
}

// ---------- layernorm (no affine) of fp32 audio -> bf16 ----------
__global__ __launch_bounds__(256)
void ln_audio_kernel(const float* __restrict__ x, u16* __restrict__ out) {
    int wave = threadIdx.x >> 6, lane = threadIdx.x & 63;
    long row = (long)blockIdx.x * 4 + wave;
    const float* xr = x + row * F_ + lane * 8;
    float4 p0 = *reinterpret_cast<const float4*>(xr);
    float4 p1 = *reinterpret_cast<const float4*>(xr + 4);
    float v[8] = {p0.x, p0.y, p0.z, p0.w, p1.x, p1.y, p1.z, p1.w};
    float s = 0.f, s2 = 0.f;
    #pragma unroll
    for (int j = 0; j < 8; j++) { s += v[j]; s2 += v[j] * v[j]; }
    for (int d = 32; d; d >>= 1) { s += __shfl_xor(s, d); s2 += __shfl_xor(s2, d); }
    float mean = s * (1.0f / F_);
    float var  = s2 * (1.0f / F_) - mean * mean;
    float rs = rsqrtf(var + EPS_);
    short8 o;
    #pragma unroll
    for (int j = 0; j < 8; j++) o[j] = (short)f2bf((v[j] - mean) * rs);
    *reinterpret_cast<short8*>(out + row * F_ + lane * 8) = o;
}

// ---------- u = std(s) * scale[b] + shift[b], bf16 in/out ----------
__global__ __launch_bounds__(256)
void ln_scale_kernel(const u16* __restrict__ sin_, const float* __restrict__ scale,
                     const float* __restrict__ shift, u16* __restrict__ out) {
    int wave = threadIdx.x >> 6, lane = threadIdx.x & 63;
    long row = (long)blockIdx.x * 4 + wave;
    int b = (int)(row >> 12);    // row / L_
    short8 xv = *reinterpret_cast<const short8*>(sin_ + row * H_ + lane * 8);
    float v[8];
    #pragma unroll
    for (int j = 0; j < 8; j++) v[j] = bf2f((u16)xv[j]);
    float s = 0.f, s2 = 0.f;
    #pragma unroll
    for (int j = 0; j < 8; j++) { s += v[j]; s2 += v[j] * v[j]; }
    for (int d = 32; d; d >>= 1) { s += __shfl_xor(s, d); s2 += __shfl_xor(s2, d); }
    float mean = s * (1.0f / H_);
    float var  = s2 * (1.0f / H_) - mean * mean;
    float rs = rsqrtf(var + EPS_);
    short8 o;
    #pragma unroll
    for (int j = 0; j < 8; j++) {
        int h = lane * 8 + j;
        o[j] = (short)f2bf((v[j] - mean) * rs * scale[b * H_ + h] + shift[b * H_ + h]);
    }
    *reinterpret_cast<short8*>(out + row * H_ + lane * 8) = o;
}

// ---------- scan: x[t] = a[t]*x[t-1] + Bu[t], a = reset ? 0 : lam_bar ----------
__global__ __launch_bounds__(256)
void scan_phase1(const u16* __restrict__ bu, const unsigned char* __restrict__ reset,
                 const float* __restrict__ lamb, float2* __restrict__ Achunk,
                 float2* __restrict__ xlast) {
    int p = threadIdx.x;
    int c = blockIdx.x & (NCH - 1);
    int b = blockIdx.x >> 7;            // NCH == 128
    float lbr = lamb[p * 2], lbi = lamb[p * 2 + 1];
    float xr = 0.f, xi = 0.f, Ar = 1.f, Ai = 0.f;
    long base = (long)b * L_ + c * CLEN;
    for (int i = 0; i < CLEN; i++) {
        long l = base + i;
        float br = bf2f(bu[l * 512 + p]);
        float bi = bf2f(bu[l * 512 + 256 + p]);
        bool r = reset[l] != 0;
        float ar = r ? 0.f : lbr, ai = r ? 0.f : lbi;
        float nxr = ar * xr - ai * xi + br;
        float nxi = ar * xi + ai * xr + bi;
        float nAr = ar * Ar - ai * Ai;
        float nAi = ar * Ai + ai * Ar;
        xr = nxr; xi = nxi; Ar = nAr; Ai = nAi;
    }
    long ci = ((long)b * NCH + c) * 256 + p;
    Achunk[ci] = make_float2(Ar, Ai);
    xlast[ci]  = make_float2(xr, xi);
}

// phase2: tiny serial pass over chunks (8 blocks x 256 threads, NCH steps)
__global__ void scan_phase2(const float2* __restrict__ Achunk, const float2* __restrict__ xlast,
                            float2* __restrict__ carry) {
    int p = threadIdx.x;
    int b = blockIdx.x;
    float cr = 0.f, ci = 0.f;
    for (int c = 0; c < NCH; c++) {
        long idx = ((long)b * NCH + c) * 256 + p;
        carry[idx] = make_float2(cr, ci);
        float2 A = Achunk[idx]; float2 xl = xlast[idx];
        float nr = A.x * cr - A.y * ci + xl.x;
        float ni = A.x * ci + A.y * cr + xl.y;
        cr = nr; ci = ni;
    }
}

// phase3: runs IN-PLACE on bu (each element read once then overwritten by same thread).
__global__ __launch_bounds__(256)
void scan_phase3(u16* __restrict__ bu, const unsigned char* __restrict__ reset,
                 const float* __restrict__ lamb, const float2* __restrict__ carry) {
    int p = threadIdx.x;
    int c = blockIdx.x & (NCH - 1);
    int b = blockIdx.x >> 7;
    float lbr = lamb[p * 2], lbi = lamb[p * 2 + 1];
    float2 cin = carry[((long)b * NCH + c) * 256 + p];
    float xr = cin.x, xi = cin.y;
    long base = (long)b * L_ + c * CLEN;
    for (int i = 0; i < CLEN; i++) {
        long l = base + i;
        float br = bf2f(bu[l * 512 + p]);
        float bi = bf2f(bu[l * 512 + 256 + p]);
        bool r = reset[l] != 0;
        float ar = r ? 0.f : lbr, ai = r ? 0.f : lbi;
        float nxr = ar * xr - ai * xi + br;
        float nxi = ar * xi + ai * xr + bi;
        xr = nxr; xi = nxi;
        bu[l * 512 + p]       = f2bf(xr);
        bu[l * 512 + 256 + p] = f2bf(xi);
    }
}

// ---------- heads weight pack: fragment-major headWf[16384] bf16 + headb[32] ----------
__global__ void pack_heads_kernel(const float* __restrict__ diff_W, const float* __restrict__ diff_b,
                                  const float* __restrict__ hit_W, const float* __restrict__ hit_b,
                                  const float* __restrict__ slider_W, const float* __restrict__ slider_b,
                                  const float* __restrict__ pos_W, const float* __restrict__ pos_b,
                                  const float* __restrict__ scal_W, const float* __restrict__ scal_b,
                                  u16* __restrict__ headWf, float* __restrict__ headb) {
    int i = blockIdx.x * 256 + threadIdx.x;   // 16384
    int ks = i >> 10;
    int r1 = i & 1023;
    int n16 = r1 >> 9;
    int r2 = r1 & 511;
    int ln = r2 >> 3;
    int j = r2 & 7;
    int kseg = ln >> 4, row = ln & 15;
    int n = n16 * 16 + row;
    int k = ks * 32 + kseg * 8 + j;
    float v = 0.f;
    if (n < 4)       v = diff_W[k * 4 + n];
    else if (n < 8)  v = hit_W[k * 4 + (n - 4)];
    else if (n < 12) v = slider_W[k * 4 + (n - 8)];
    else if (n < 14) v = pos_W[k * 2 + (n - 12)];
    else if (n < 18) v = scal_W[k * 4 + (n - 14)];
    headWf[i] = f2bf(v);
    if (i < 32) {
        float b = 0.f;
        if (i < 4)       b = diff_b[i];
        else if (i < 8)  b = hit_b[i - 4];
        else if (i < 12) b = slider_b[i - 8];
        else if (i < 14) b = pos_b[i - 12];
        else if (i < 18) b = scal_b[i - 14];
        headb[i] = b;
    }
}

// ---------- heads MFMA GEMM: out-scatter of u[M,512] @ headW[32,512]^T ----------
__global__ __launch_bounds__(256)
void heads_mfma_kernel(const u16* __restrict__ u, const u16* __restrict__ headWf,
                       const float* __restrict__ headb, float* __restrict__ out) {
    __shared__ u16 lB[16384];   // 32 KB, fragment-major, staged once (flat copy)
    __shared__ u16 lA[4096];    // 8 KB, row-major [128][32]
    const int tid  = threadIdx.x;
    const int lane = tid & 63;
    const int wave = tid >> 6;
    const int quad = lane >> 4;
    const int l16  = lane & 15;
    const long bm = (long)blockIdx.x * 128;

    #pragma unroll
    for (int t = 0; t < 8; t++) {
        int blk = wave * 8 + t;
        __builtin_amdgcn_global_load_lds((gas_p)(headWf + blk * 512 + lane * 8),
                                         (las_p)(&lB[blk * 512 + lane * 8]), 16, 0, 0);
    }

    floatx4 acc[2][2] = {};
    const int r0 = tid >> 2;
    const int c0 = (tid & 3) * 8;
    const u16* a0 = u + (bm + r0)      * 512L + c0;
    const u16* a1 = u + (bm + r0 + 64) * 512L + c0;

    for (int ks = 0; ks < 16; ks++) {
        __builtin_amdgcn_global_load_lds((gas_p)(a0 + ks * 32), (las_p)(&lA[tid * 8]),         16, 0, 0);
        __builtin_amdgcn_global_load_lds((gas_p)(a1 + ks * 32), (las_p)(&lA[(tid + 256) * 8]), 16, 0, 0);
        __syncthreads();
        short8 afr[2], bfr[2];
        #pragma unroll
        for (int mm = 0; mm < 2; mm++)
            afr[mm] = *reinterpret_cast<const short8*>(&lA[(wave * 32 + mm * 16 + l16) * 32 + quad * 8]);
        #pragma unroll
        for (int nn = 0; nn < 2; nn++)
            bfr[nn] = *reinterpret_cast<const short8*>(&lB[ks * 1024 + nn * 512 + lane * 8]);
        #pragma unroll
        for (int mm = 0; mm < 2; mm++)
            #pragma unroll
            for (int nn = 0; nn < 2; nn++)
                acc[mm][nn] = __builtin_amdgcn_mfma_f32_16x16x32_bf16(afr[mm], bfr[nn], acc[mm][nn], 0, 0, 0);
        __syncthreads();
    }

    float* pos_o    = out;            // [B,L,2]
    float* combo_o  = out + 65536;    // [B,L]
    float* curve_o  = out + 98304;
    float* timing_o = out + 131072;
    float* rep_o    = out + 163840;
    float* hit_o    = out + 196608;   // [B,L,4]
    float* slider_o = out + 327680;
    float* diff_o   = out + 458752;

    #pragma unroll
    for (int nn = 0; nn < 2; nn++) {
        const int col = nn * 16 + l16;
        if (col >= 18) continue;
        const float bv = headb[col];
        #pragma unroll
        for (int mm = 0; mm < 2; mm++) {
            #pragma unroll
            for (int r = 0; r < 4; r++) {
                const long row = bm + wave * 32 + mm * 16 + quad * 4 + r;
                float v = acc[mm][nn][r] + bv;
                if (col < 4)       diff_o[row * 4 + col] = tanh_f(v);
                else if (col < 8)  hit_o[row * 4 + (col - 4)] = v;
                else if (col < 12) slider_o[row * 4 + (col - 8)] = v;
                else if (col < 14) pos_o[row * 2 + (col - 12)] = tanh_f(v);
                else if (col == 14) timing_o[row] = v;
                else if (col == 15) combo_o[row] = v;
                else if (col == 16) curve_o[row] = v;
                else                rep_o[row] = __builtin_amdgcn_exp2f(fmaxf(v, 0.0f));
            }
        }
    }
}

// =======================================================================
extern "C" void kernel_launch(void* const* d_in, const int* in_sizes, int n_in,
                              void* d_out, int out_size, void* d_ws, size_t ws_size,
                              hipStream_t stream) {
    const float* raw_audio = (const float*)d_in[0];
    const int*   seq_ids   = (const int*)d_in[1];
    const float* diffr     = (const float*)d_in[2];
    const float* favs      = (const float*)d_in[3];
    const float* in_W      = (const float*)d_in[4];
    const float* in_b      = (const float*)d_in[5];
    const float* shift_W   = (const float*)d_in[6];
    const float* shift_b   = (const float*)d_in[7];
    const float* scale_W   = (const float*)d_in[8];
    const float* scale_b   = (const float*)d_in[9];
    const float* lam_re    = (const float*)d_in[10];
    const float* lam_im    = (const float*)d_in[11];
    const float* log_dt    = (const float*)d_in[12];
    const float* B_re      = (const float*)d_in[13];
    const float* B_im      = (const float*)d_in[14];
    const float* C_re      = (const float*)d_in[15];
    const float* C_im      = (const float*)d_in[16];
    const float* Dp        = (const float*)d_in[17];
    const float* ffn_W1    = (const float*)d_in[18];
    const float* ffn_b1    = (const float*)d_in[19];
    const float* ffn_W2    = (const float*)d_in[20];
    const float* ffn_b2    = (const float*)d_in[21];
    const float* diff_W    = (const float*)d_in[22];
    const float* diff_b    = (const float*)d_in[23];
    const float* hit_W     = (const float*)d_in[24];
    const float* hit_b     = (const float*)d_in[25];
    const float* slider_W  = (const float*)d_in[26];
    const float* slider_b  = (const float*)d_in[27];
    const float* pos_W     = (const float*)d_in[28];
    const float* pos_b     = (const float*)d_in[29];
    const float* scal_W    = (const float*)d_in[30];
    const float* scal_b    = (const float*)d_in[31];

    char* ws = (char*)d_ws;
    size_t off = 0;
    auto alloc = [&](size_t bytes) -> void* {
        void* p = ws + off; off += (bytes + 255) & ~(size_t)255; return p;
    };
    u16* u_b   = (u16*)alloc((size_t)M_ * H_ * 2);
    u16* z_b   = (u16*)alloc((size_t)M_ * H_ * 2);
    u16* bu_b  = (u16*)alloc((size_t)M_ * H_ * 2);
    u16* ff1_b = (u16*)alloc((size_t)M_ * 1024 * 2);
    u16* lnA_b = ff1_b;    // alias: lnA only live before layer 0's FFN1
    u16* x_b   = bu_b;     // alias: scan output in-place over Bu
    u16* s_b   = bu_b;     // alias: FFN2 output reuses Bu slot
    u16* inWT  = (u16*)alloc((size_t)H_ * F_ * 2);
    u16* wbu   = (u16*)alloc((size_t)DEPTH_ * 512 * H_ * 2);
    u16* wc    = (u16*)alloc((size_t)DEPTH_ * H_ * 512 * 2);
    u16* w1t   = (u16*)alloc((size_t)DEPTH_ * 1024 * H_ * 2);
    u16* w2t   = (u16*)alloc((size_t)DEPTH_ * H_ * 1024 * 2);
    float* lamb = (float*)alloc((size_t)DEPTH_ * P_ * 2 * 4);
    unsigned char* rst = (unsigned char*)alloc(M_);
    float* shift_all = (float*)alloc((size_t)DEPTH_ * B_ * H_ * 4);
    float* scale_all = (float*)alloc((size_t)DEPTH_ * B_ * H_ * 4);
    float2* Achunk = (float2*)alloc((size_t)B_ * NCH * P_ * 8);
    float2* xlastc = (float2*)alloc((size_t)B_ * NCH * P_ * 8);
    float2* carryc = (float2*)alloc((size_t)B_ * NCH * P_ * 8);
    u16* headWf = (u16*)alloc((size_t)16384 * 2);
    float* headb = (float*)alloc(32 * 4);
    (void)in_sizes; (void)n_in; (void)out_size; (void)ws_size;

    // ---- weight / constant prep ----
    reset_kernel<<<M_ / 256, 256, 0, stream>>>(seq_ids, rst);
    lamb_kernel<<<(DEPTH_ * P_ + 255) / 256, 256, 0, stream>>>(lam_re, lam_im, log_dt, lamb);
    wbu_kernel<<<(DEPTH_ * P_ * H_) / 256, 256, 0, stream>>>(lam_re, lam_im, lamb, B_re, B_im, wbu);
    wc_kernel<<<(DEPTH_ * H_ * 512) / 256, 256, 0, stream>>>(C_re, C_im, wc);
    pack_bt_kernel<<<(F_ * H_) / 256, 256, 0, stream>>>(in_W, inWT, 512, 512, (long)F_ * H_);
    pack_bt_kernel<<<(DEPTH_ * H_ * 1024) / 256, 256, 0, stream>>>(ffn_W1, w1t, 512, 1024,
                                                                   (long)DEPTH_ * H_ * 1024);
    pack_bt_kernel<<<(DEPTH_ * 1024 * H_) / 256, 256, 0, stream>>>(ffn_W2, w2t, 1024, 512,
                                                                   (long)DEPTH_ * 1024 * H_);
    modk_kernel<<<(DEPTH_ * B_ * H_) / 256, 256, 0, stream>>>(diffr, favs, shift_W, shift_b,
                                                              scale_W, scale_b, shift_all, scale_all);
    pack_heads_kernel<<<16384 / 256, 256, 0, stream>>>(diff_W, diff_b, hit_W, hit_b,
                                                       slider_W, slider_b, pos_W, pos_b,
                                                       scal_W, scal_b, headWf, headb);

    // ---- stem: u = std(audio) @ in_W + in_b ----
    ln_audio_kernel<<<M_ / 4, 256, 0, stream>>>(raw_audio, lnA_b);
    const int g512  = (M_ / BM) * (512 / BN);    // 1024 blocks, XCD-swizzled 1D
    const int g1024 = (M_ / BM) * (1024 / BN);   // 2048 blocks
    gemm_nt_kernel<EPI_BIAS><<<g512, 256, 0, stream>>>(lnA_b, inWT, u_b, in_b, nullptr, nullptr,
                                                       M_, H_, F_);

    // ---- layers ----
    for (int l = 0; l < DEPTH_; l++) {
        gemm_nt_kernel<EPI_STORE><<<g512, 256, 0, stream>>>(u_b, wbu + (size_t)l * 512 * H_, bu_b,
                                                            nullptr, nullptr, nullptr, M_, 512, H_);
        scan_phase1<<<B_ * NCH, 256, 0, stream>>>(bu_b, rst, lamb + l * P_ * 2, Achunk, xlastc);
        scan_phase2<<<B_, 256, 0, stream>>>(Achunk, xlastc, carryc);
        scan_phase3<<<B_ * NCH, 256, 0, stream>>>(bu_b, rst, lamb + l * P_ * 2, carryc);
        gemm_nt_kernel<EPI_DU_GELU_RES><<<g512, 256, 0, stream>>>(x_b, wc + (size_t)l * H_ * 512, z_b,
                                                                  nullptr, Dp + (size_t)l * H_, u_b,
                                                                  M_, H_, 512);
        gemm_nt_kernel<EPI_BIAS_GELU><<<g1024, 256, 0, stream>>>(z_b, w1t + (size_t)l * 1024 * H_, ff1_b,
                                                                 ffn_b1 + (size_t)l * 1024, nullptr, nullptr,
                                                                 M_, 1024, H_);
        gemm_nt_kernel<EPI_BIAS_RES><<<g512, 256, 0, stream>>>(ff1_b, w2t + (size_t)l * H_ * 1024, s_b,
                                                               ffn_b2 + (size_t)l * H_, nullptr, z_b,
                                                               M_, H_, 1024);
        ln_scale_kernel<<<M_ / 4, 256, 0, stream>>>(s_b, scale_all + (size_t)l * B_ * H_,
                                                    shift_all + (size_t)l * B_ * H_, u_b);
    }

    // ---- heads ----
    heads_mfma_kernel<<<M_ / 128, 256, 0, stream>>>(u_b, headWf, headb, (float*)d_out);
}